// Round 8
// baseline (7773.485 us; speedup 1.0000x reference)
//
#include <hip/hip_runtime.h>
#include <hip/hip_fp16.h>

#define NTRAJ   256
#define NTP     512
#define NSTEPS  511
#define LATENT  256
#define INPUT   128
#define DEC_OUT 128

#define OUT_VOL ((size_t)NTRAJ * LATENT)                              // 65536
#define OUT_DTS (OUT_VOL + (size_t)NTRAJ * NSTEPS * DEC_OUT)          // 16809984

// Pair-interleaved fp16 weight workspace (offsets in uint32 = half2 units).
// Layout per matrix [K][C]: ws[kp*C + c] = half2(W[2kp][c], W[2kp+1][c]).
#define WU_UG1  0
#define WU_UG2  49152
#define WU_UGT1 81920
#define WU_UGT2 131072
#define WU_RG1  163840
#define WU_RG2  212992
#define WU_NS1  245760
#define WU_NS2  294912
#define WU_DK1  327680
#define WU_DEC  360448
#define WU_TOT  376832

typedef _Float16 h2_t __attribute__((ext_vector_type(2)));
union U32H2 { unsigned int u; h2_t h; };

__device__ __forceinline__ float dot2f(unsigned int wu, unsigned int xu, float acc) {
#if defined(__has_builtin) && __has_builtin(__builtin_amdgcn_fdot2)
    U32H2 a, b; a.u = wu; b.u = xu;
    return __builtin_amdgcn_fdot2(a.h, b.h, acc, false);
#else
    U32H2 a, b; a.u = wu; b.u = xu;
    return acc + (float)a.h.x * (float)b.h.x + (float)a.h.y * (float)b.h.y;
#endif
}

__device__ __forceinline__ float wred(float v) {
    #pragma unroll
    for (int off = 32; off; off >>= 1) v += __shfl_down(v, off, 64);
    return v;
}
__device__ __forceinline__ float fast_sigmoid(float x) { return 1.0f / (1.0f + __expf(-x)); }
__device__ __forceinline__ float fast_tanh(float x) {
    float e = __expf(2.0f * x);
    return 1.0f - 2.0f / (e + 1.0f);
}
// Pack (v_even, v_odd) from adjacent lanes into one half2; only even lanes
// hold the correct result and write. Must be called by full waves.
__device__ __forceinline__ unsigned int packpair(float v) {
    float vn = __shfl_xor(v, 1, 64);
    U32H2 r; r.h.x = (_Float16)v; r.h.y = (_Float16)vn;
    return r.u;
}

// ---- weight prep: fp32 -> k-pair-interleaved half2 ----
extern "C" __global__ void __launch_bounds__(256)
convert_w(const float* __restrict__ ug_w1, const float* __restrict__ ug_w2,
          const float* __restrict__ ugt_w1, const float* __restrict__ ugt_w2,
          const float* __restrict__ rg_w1, const float* __restrict__ rg_w2,
          const float* __restrict__ ns_w1, const float* __restrict__ ns_w2,
          const float* __restrict__ dk_w1, const float* __restrict__ dec_w,
          unsigned int* __restrict__ ws)
{
    const int i = blockIdx.x * 256 + threadIdx.x;
    const float* s; int o; int cbits;
    if      (i < WU_UG2)  { s = ug_w1;  o = i;           cbits = 8; }
    else if (i < WU_UGT1) { s = ug_w2;  o = i - WU_UG2;  cbits = 8; }
    else if (i < WU_UGT2) { s = ugt_w1; o = i - WU_UGT1; cbits = 8; }
    else if (i < WU_RG1)  { s = ugt_w2; o = i - WU_UGT2; cbits = 8; }
    else if (i < WU_RG2)  { s = rg_w1;  o = i - WU_RG1;  cbits = 8; }
    else if (i < WU_NS1)  { s = rg_w2;  o = i - WU_RG2;  cbits = 8; }
    else if (i < WU_NS2)  { s = ns_w1;  o = i - WU_NS1;  cbits = 8; }
    else if (i < WU_DK1)  { s = ns_w2;  o = i - WU_NS2;  cbits = 8; }
    else if (i < WU_DEC)  { s = dk_w1;  o = i - WU_DK1;  cbits = 8; }
    else                  { s = dec_w;  o = i - WU_DEC;  cbits = 7; }
    const int C  = 1 << cbits;
    const int kp = o >> cbits;
    const int c  = o & (C - 1);
    const float v0 = s[(2 * kp) * C + c];
    const float v1 = s[(2 * kp + 1) * C + c];
    const unsigned int h0 = __half_as_ushort(__float2half(v0));
    const unsigned int h1 = __half_as_ushort(__float2half(v1));
    ws[i] = h0 | (h1 << 16);
}

// Macro hygiene: no parameter named x/y/z/w (body does member access).
#define DOT1(acc, wv, xv) { \
    acc.x = dot2f((wv).x, (xv), acc.x); acc.y = dot2f((wv).y, (xv), acc.y); \
    acc.z = dot2f((wv).z, (xv), acc.z); acc.w = dot2f((wv).w, (xv), acc.w); }

extern "C" __global__ void __launch_bounds__(512, 2)
rnn_decay_kernel8(const float* __restrict__ data, const float* __restrict__ ts,
                  const float* __restrict__ ug_b1, const float* __restrict__ ug_b2,
                  const float* __restrict__ ugt_b1, const float* __restrict__ ugt_b2,
                  const float* __restrict__ rg_b1, const float* __restrict__ rg_b2,
                  const float* __restrict__ ns_b1, const float* __restrict__ ns_b2,
                  const float* __restrict__ dk_b1, const float* __restrict__ dk_w2,
                  const float* __restrict__ dk_b2, const float* __restrict__ dec_b,
                  const unsigned int* __restrict__ wsu, float* __restrict__ out)
{
    // Trajectory-batched (B=2) version of the verified R0 K-split structure:
    // grid = 128 blocks; each block runs TWO trajectories, loading each weight
    // uint4 ONCE and dotting it against both trajectories' activations.
    // Per-XCD weight traffic halves (the L2-roofline hypothesis test).
    // Thread group h = tid>>8 owns trajectory (2*blockIdx.x + h)'s pointwise
    // state in registers; GEMV phases are block-wide over both banks.
    __shared__ __align__(16) float s_part[2][8192];     // per-traj partial banks
    __shared__ __align__(16) unsigned int s_in_h[2][192];
    __shared__ __align__(16) unsigned int s_ns_h[2][192];
    __shared__ __align__(16) unsigned int s_y_h[2][128];
    __shared__ __align__(16) unsigned int s_a_h[2][128];
    __shared__ __align__(16) unsigned int s_b_h[2][128];
    __shared__ __align__(16) unsigned int s_c_h[2][128];
    __shared__ __align__(16) unsigned int s_v_h[2][128];
    __shared__ float s_red[2][8];                       // [h][0..3] mask, [4..7] dk

    const int tid  = threadIdx.x;
    const int w    = tid >> 6;                  // wave 0..7
    const int lane = tid & 63;
    const int c    = tid & 255;
    const int h    = tid >> 8;                  // trajectory group 0/1
    const int wg   = w & 3;                     // wave within group
    const int cl4  = lane << 2;                 // 4 uint cols per lane (1KB/wave)
    const int traj = (blockIdx.x << 1) + h;     // this thread's pointwise traj

    const unsigned int* UG1  = wsu + WU_UG1;  const unsigned int* UG2  = wsu + WU_UG2;
    const unsigned int* UGT1 = wsu + WU_UGT1; const unsigned int* UGT2 = wsu + WU_UGT2;
    const unsigned int* RG1  = wsu + WU_RG1;  const unsigned int* RG2  = wsu + WU_RG2;
    const unsigned int* NS1  = wsu + WU_NS1;  const unsigned int* NS2  = wsu + WU_NS2;
    const unsigned int* DK1  = wsu + WU_DK1;  const unsigned int* DECW = wsu + WU_DEC;

    const float* dbase = data + (size_t)traj * NTP * (2 * INPUT);
    const float* tbase = ts + (size_t)traj * NTP;
    float* vol_out = out + OUT_VOL + (size_t)traj * NSTEPS * DEC_OUT;
    float* dts_out = out + OUT_DTS + (size_t)traj * NSTEPS;

    for (int t0 = c; t0 < NSTEPS; t0 += 256)
        dts_out[t0] = tbase[t0 + 1] - tbase[t0];

    float r_y = 0.f, r_yt = 0.f;                // state of (traj h, col c)

    const int kp24 = w * 24;                    // K=384 GEMVs: 24 kp per wave
    const int kp16 = w << 4;                    // K=256 GEMVs: 16 kp per wave

    for (int t = -1; t < NSTEPS; ++t) {
        const bool first = (t < 0);

        // ---- stage x, mask partials, xh pack (each group its own traj) ----
        {
            const float xval = first ? dbase[c] : dbase[(size_t)(t + 1) * 256 + c];
            float mv = (c >= 128) ? xval : 0.f;
            mv = wred(mv);
            if (lane == 0) s_red[h][wg] = mv;
            if (c < 128) {
                const unsigned int px = packpair(xval);
                if (!(lane & 1)) { s_in_h[h][128 + (c >> 1)] = px; s_ns_h[h][128 + (c >> 1)] = px; }
            }
            if (first && !(lane & 1)) s_in_h[h][c >> 1] = 0u;   // ydec = 0
        }

        float r_ydec = 0.f, r_u = 0.f, r_ut = 0.f;
        bool maskv;

        if (!first) {
            // ---- dk1: y @ dk_w1, K=256 — load weight once, dot both trajs ----
            {
                float4 a0 = make_float4(0.f, 0.f, 0.f, 0.f), a1 = a0;
                #pragma unroll 4
                for (int i = 0; i < 16; ++i) {
                    const int kp = kp16 + i;
                    const unsigned int x0 = s_y_h[0][kp];
                    const unsigned int x1 = s_y_h[1][kp];
                    const uint4 wv = *(const uint4*)(DK1 + (size_t)kp * 256 + cl4);
                    DOT1(a0, wv, x0); DOT1(a1, wv, x1);
                }
                *(float4*)(&s_part[0][(w << 8) + cl4]) = a0;
                *(float4*)(&s_part[1][(w << 8) + cl4]) = a1;
            }
            __syncthreads();                                           // B1
            {
                float v = dk_b1[c];
                #pragma unroll
                for (int i = 0; i < 8; ++i) v += s_part[h][(i << 8) + c];
                v = fmaxf(v, 0.f);
                const float pv = wred(v * dk_w2[c]);
                if (lane == 0) s_red[h][4 + wg] = pv;
            }
            __syncthreads();                                           // B2
            maskv = (s_red[h][0] + s_red[h][1] + s_red[h][2] + s_red[h][3]) > 0.f;
            {
                const float decay = fmaxf(s_red[h][4] + s_red[h][5] + s_red[h][6]
                                        + s_red[h][7] + dk_b2[0], 0.f);
                const float dt = tbase[t + 1] - tbase[t];
                const float diff = r_y - r_yt;
                const float ef = __expf(-decay * dt);
                const float eh = __expf(-0.5f * decay * dt);
                r_ydec = r_yt + diff * ef;
                const float vol = 0.5f * (r_y + r_yt + diff * eh);
                const unsigned int pd  = packpair(r_ydec);
                const unsigned int pvv = packpair(vol);
                if (!(lane & 1)) { s_in_h[h][c >> 1] = pd; s_v_h[h][c >> 1] = pvv; }
            }
            __syncthreads();                                           // B3
        } else {
            __syncthreads();                                           // B3
            maskv = (s_red[h][0] + s_red[h][1] + s_red[h][2] + s_red[h][3]) > 0.f;
        }

        // ---- dec (K=256, src s_v_h; weight loaded once, both trajs) ----
        if (!first) {
            float4 e0 = make_float4(0.f, 0.f, 0.f, 0.f), e1 = e0;
            const int hh = lane >> 5, cl = (lane & 31) << 2;
            const int kpb = kp16 + hh;
            #pragma unroll 4
            for (int i = 0; i < 8; ++i) {
                const int kp = kpb + (i << 1);
                const uint4 wv = *(const uint4*)(DECW + (size_t)kp * 128 + cl);
                const unsigned int x0 = s_v_h[0][kp];
                const unsigned int x1 = s_v_h[1][kp];
                DOT1(e0, wv, x0); DOT1(e1, wv, x1);
            }
            const int slot = 6144 + ((w << 1) + hh) * 128 + cl;
            *(float4*)(&s_part[0][slot]) = e0;
            *(float4*)(&s_part[1][slot]) = e1;
        }

        // ---- group1: ug1/ugt1/rg1 (K=384) — 3 loads, 6 dot sets ----
        {
            float4 aA0 = make_float4(0.f, 0.f, 0.f, 0.f), aB0 = aA0, aC0 = aA0;
            float4 aA1 = aA0, aB1 = aA0, aC1 = aA0;
            #pragma unroll 4
            for (int i = 0; i < 24; ++i) {
                const int kp = kp24 + i;
                const unsigned int x0 = s_in_h[0][kp];
                const unsigned int x1 = s_in_h[1][kp];
                const uint4 wa = *(const uint4*)(UG1  + (size_t)kp * 256 + cl4);
                const uint4 wb = *(const uint4*)(UGT1 + (size_t)kp * 256 + cl4);
                const uint4 wc = *(const uint4*)(RG1  + (size_t)kp * 256 + cl4);
                DOT1(aA0, wa, x0); DOT1(aA1, wa, x1);
                DOT1(aB0, wb, x0); DOT1(aB1, wb, x1);
                DOT1(aC0, wc, x0); DOT1(aC1, wc, x1);
            }
            *(float4*)(&s_part[0][(w << 8) + cl4])        = aA0;
            *(float4*)(&s_part[0][2048 + (w << 8) + cl4]) = aB0;
            *(float4*)(&s_part[0][4096 + (w << 8) + cl4]) = aC0;
            *(float4*)(&s_part[1][(w << 8) + cl4])        = aA1;
            *(float4*)(&s_part[1][2048 + (w << 8) + cl4]) = aB1;
            *(float4*)(&s_part[1][4096 + (w << 8) + cl4]) = aC1;
        }
        __syncthreads();                                               // B4
        {   // per-group reduce of its own traj bank: ug, ugt, rg (+dec out)
            float v = ug_b1[c];
            #pragma unroll
            for (int i = 0; i < 8; ++i) v += s_part[h][(i << 8) + c];
            v = fast_tanh(v);
            const unsigned int pka = packpair(v);
            if (!(lane & 1)) s_a_h[h][c >> 1] = pka;
            float v2 = ugt_b1[c];
            #pragma unroll
            for (int i = 0; i < 8; ++i) v2 += s_part[h][2048 + (i << 8) + c];
            v2 = fast_tanh(v2);
            const unsigned int pkb = packpair(v2);
            if (!(lane & 1)) s_b_h[h][c >> 1] = pkb;
            float v3 = rg_b1[c];
            #pragma unroll
            for (int i = 0; i < 8; ++i) v3 += s_part[h][4096 + (i << 8) + c];
            v3 = fast_tanh(v3);
            const unsigned int pkc = packpair(v3);
            if (!(lane & 1)) s_c_h[h][c >> 1] = pkc;
            if (!first && c < 128) {
                float vd = dec_b[c];
                #pragma unroll
                for (int i = 0; i < 16; ++i) vd += s_part[h][6144 + (i << 7) + c];
                vol_out[(size_t)t * DEC_OUT + c] = vd;
            }
        }
        __syncthreads();                                               // B5

        // ---- group2: ug2/ugt2/rg2 (K=256) ----
        {
            float4 aA0 = make_float4(0.f, 0.f, 0.f, 0.f), aB0 = aA0, aC0 = aA0;
            float4 aA1 = aA0, aB1 = aA0, aC1 = aA0;
            #pragma unroll 4
            for (int i = 0; i < 16; ++i) {
                const int kp = kp16 + i;
                const unsigned int xa0 = s_a_h[0][kp], xa1 = s_a_h[1][kp];
                const unsigned int xb0 = s_b_h[0][kp], xb1 = s_b_h[1][kp];
                const unsigned int xc0 = s_c_h[0][kp], xc1 = s_c_h[1][kp];
                const uint4 wa = *(const uint4*)(UG2  + (size_t)kp * 256 + cl4);
                const uint4 wb = *(const uint4*)(UGT2 + (size_t)kp * 256 + cl4);
                const uint4 wc = *(const uint4*)(RG2  + (size_t)kp * 256 + cl4);
                DOT1(aA0, wa, xa0); DOT1(aA1, wa, xa1);
                DOT1(aB0, wb, xb0); DOT1(aB1, wb, xb1);
                DOT1(aC0, wc, xc0); DOT1(aC1, wc, xc1);
            }
            *(float4*)(&s_part[0][(w << 8) + cl4])        = aA0;
            *(float4*)(&s_part[0][2048 + (w << 8) + cl4]) = aB0;
            *(float4*)(&s_part[0][4096 + (w << 8) + cl4]) = aC0;
            *(float4*)(&s_part[1][(w << 8) + cl4])        = aA1;
            *(float4*)(&s_part[1][2048 + (w << 8) + cl4]) = aB1;
            *(float4*)(&s_part[1][4096 + (w << 8) + cl4]) = aC1;
        }
        __syncthreads();                                               // B6
        {   // u, ut stay in-register for the owning thread; r packs ns input
            float v = ug_b2[c];
            #pragma unroll
            for (int i = 0; i < 8; ++i) v += s_part[h][(i << 8) + c];
            r_u = fast_sigmoid(v);
            float v2 = ugt_b2[c];
            #pragma unroll
            for (int i = 0; i < 8; ++i) v2 += s_part[h][2048 + (i << 8) + c];
            r_ut = fast_sigmoid(v2);
            float v3 = rg_b2[c];
            #pragma unroll
            for (int i = 0; i < 8; ++i) v3 += s_part[h][4096 + (i << 8) + c];
            const float rr = fast_sigmoid(v3);
            const unsigned int pk = packpair(r_ydec * rr);
            if (!(lane & 1)) s_ns_h[h][c >> 1] = pk;   // first step: ydec=0 ✓
        }
        __syncthreads();                                               // B7

        // ---- ns1 (K=384, src s_ns_h) ----
        {
            float4 a0 = make_float4(0.f, 0.f, 0.f, 0.f), a1 = a0;
            #pragma unroll 4
            for (int i = 0; i < 24; ++i) {
                const int kp = kp24 + i;
                const unsigned int x0 = s_ns_h[0][kp];
                const unsigned int x1 = s_ns_h[1][kp];
                const uint4 wa = *(const uint4*)(NS1 + (size_t)kp * 256 + cl4);
                DOT1(a0, wa, x0); DOT1(a1, wa, x1);
            }
            *(float4*)(&s_part[0][(w << 8) + cl4]) = a0;
            *(float4*)(&s_part[1][(w << 8) + cl4]) = a1;
        }
        __syncthreads();                                               // B8
        {
            float v = ns_b1[c];
            #pragma unroll
            for (int i = 0; i < 8; ++i) v += s_part[h][(i << 8) + c];
            v = fast_tanh(v);
            const unsigned int pk = packpair(v);
            if (!(lane & 1)) s_a_h[h][c >> 1] = pk;
        }
        __syncthreads();                                               // B9

        // ---- ns2 (K=256, src s_a_h) + state update ----
        {
            float4 a0 = make_float4(0.f, 0.f, 0.f, 0.f), a1 = a0;
            #pragma unroll 4
            for (int i = 0; i < 16; ++i) {
                const int kp = kp16 + i;
                const unsigned int x0 = s_a_h[0][kp];
                const unsigned int x1 = s_a_h[1][kp];
                const uint4 wa = *(const uint4*)(NS2 + (size_t)kp * 256 + cl4);
                DOT1(a0, wa, x0); DOT1(a1, wa, x1);
            }
            *(float4*)(&s_part[0][(w << 8) + cl4]) = a0;
            *(float4*)(&s_part[1][(w << 8) + cl4]) = a1;
        }
        __syncthreads();                                               // B10
        {
            float nsv = ns_b2[c];
            #pragma unroll
            for (int i = 0; i < 8; ++i) nsv += s_part[h][(i << 8) + c];
            const float ny  = (1.f - r_u)  * nsv + r_u  * r_ydec;
            const float nyt = (1.f - r_ut) * nsv + r_ut * r_yt;
            r_y  = maskv ? ny  : r_ydec;
            r_yt = maskv ? nyt : r_yt;
            const unsigned int pk = packpair(r_y);
            if (!(lane & 1)) s_y_h[h][c >> 1] = pk;
        }
        __syncthreads();                                               // B11
    }

    out[(size_t)traj * 256 + c] = r_y;
}

extern "C" void kernel_launch(void* const* d_in, const int* in_sizes, int n_in,
                              void* d_out, int out_size, void* d_ws, size_t ws_size,
                              hipStream_t stream) {
    const float* data   = (const float*)d_in[0];
    const float* ts     = (const float*)d_in[1];
    const float* ug_w1  = (const float*)d_in[2];
    const float* ug_b1  = (const float*)d_in[3];
    const float* ug_w2  = (const float*)d_in[4];
    const float* ug_b2  = (const float*)d_in[5];
    const float* ugt_w1 = (const float*)d_in[6];
    const float* ugt_b1 = (const float*)d_in[7];
    const float* ugt_w2 = (const float*)d_in[8];
    const float* ugt_b2 = (const float*)d_in[9];
    const float* rg_w1  = (const float*)d_in[10];
    const float* rg_b1  = (const float*)d_in[11];
    const float* rg_w2  = (const float*)d_in[12];
    const float* rg_b2  = (const float*)d_in[13];
    // d_in[14..17] = rgt_* : unused by the reference
    const float* ns_w1  = (const float*)d_in[18];
    const float* ns_b1  = (const float*)d_in[19];
    const float* ns_w2  = (const float*)d_in[20];
    const float* ns_b2  = (const float*)d_in[21];
    const float* dk_w1  = (const float*)d_in[22];
    const float* dk_b1  = (const float*)d_in[23];
    const float* dk_w2  = (const float*)d_in[24];
    const float* dk_b2  = (const float*)d_in[25];
    const float* dec_w  = (const float*)d_in[26];
    const float* dec_b  = (const float*)d_in[27];

    unsigned int* wsu = (unsigned int*)d_ws;

    convert_w<<<WU_TOT / 256, 256, 0, stream>>>(ug_w1, ug_w2, ugt_w1, ugt_w2,
                                                rg_w1, rg_w2, ns_w1, ns_w2,
                                                dk_w1, dec_w, wsu);

    rnn_decay_kernel8<<<NTRAJ / 2, 512, 0, stream>>>(
        data, ts, ug_b1, ug_b2, ugt_b1, ugt_b2, rg_b1, rg_b2, ns_b1, ns_b2,
        dk_b1, dk_w2, dk_b2, dec_b, wsu, (float*)d_out);
}